// Round 1
// baseline (8524.265 us; speedup 1.0000x reference)
//
#include <hip/hip_runtime.h>
#include <math.h>

#define S_ 196
#define B_ 64
#define C_ 1024
#define H_ 1024
#define E_ 512
#define V_ 32000
#define TS_ 19   // T-1 decode steps

__device__ __forceinline__ float sigmoidf_(float x) { return 1.f / (1.f + __expf(-x)); }

// ---------------- embedding gather (transposed): yembT[t][e][b] ----------------
__global__ __launch_bounds__(256) void k_yemb(const int* __restrict__ y,
                                              const float* __restrict__ embW,
                                              float* __restrict__ yembT) {
    int t = blockIdx.x >> 6;
    int b = blockIdx.x & 63;
    int row = y[t * 64 + b];
    const float* src = embW + (long)row * E_;
    for (int e = threadIdx.x; e < E_; e += 256)
        yembT[((long)(t * E_ + e) << 6) + b] = src[e];
}

// ---------------- 1024x1024 transpose (att_hid2ctx -> attT[c][h]) ----------------
__global__ void k_transpose(const float* __restrict__ in, float* __restrict__ out) {
    __shared__ float tile[32][33];
    int bx = blockIdx.x * 32, by = blockIdx.y * 32;
    int x = threadIdx.x, y0 = threadIdx.y;
    for (int yy = y0; yy < 32; yy += 8) tile[yy][x] = in[(by + yy) * 1024 + bx + x];
    __syncthreads();
    for (int yy = y0; yy < 32; yy += 8) out[(bx + yy) * 1024 + by + x] = tile[x][yy];
}

// ---------------- ctx_proj = ctx @ att_ctx2ctx : [12544,1024]x[1024,1024] --------
// fp32 tiled GEMM: BM=128, BN=64, BK=16, 256 threads, 8x4 microtile
__global__ __launch_bounds__(256) void k_gemm_ctx(const float* __restrict__ A,
                                                  const float* __restrict__ B,
                                                  float* __restrict__ Cm) {
    __shared__ float As[16][132];
    __shared__ float Bs[16][64];
    int tid = threadIdx.x;
    int m0 = blockIdx.y * 128, n0 = blockIdx.x * 64;
    float acc[8][4];
#pragma unroll
    for (int i = 0; i < 8; i++)
#pragma unroll
        for (int j = 0; j < 4; j++) acc[i][j] = 0.f;

    int ar = tid >> 2, ac = (tid & 3) << 2;
    int br = tid >> 4, bc = (tid & 15) << 2;
    int ty = tid >> 4, tx = tid & 15;

    for (int k0 = 0; k0 < 1024; k0 += 16) {
        float4 a0 = *(const float4*)(A + (long)(m0 + ar) * 1024 + k0 + ac);
        float4 a1 = *(const float4*)(A + (long)(m0 + ar + 64) * 1024 + k0 + ac);
        float4 b0 = *(const float4*)(B + (long)(k0 + br) * 1024 + n0 + bc);
        __syncthreads();
        As[ac + 0][ar] = a0.x; As[ac + 1][ar] = a0.y; As[ac + 2][ar] = a0.z; As[ac + 3][ar] = a0.w;
        As[ac + 0][ar + 64] = a1.x; As[ac + 1][ar + 64] = a1.y; As[ac + 2][ar + 64] = a1.z; As[ac + 3][ar + 64] = a1.w;
        *(float4*)&Bs[br][bc] = b0;
        __syncthreads();
#pragma unroll
        for (int k = 0; k < 16; k++) {
            float4 x0 = *(const float4*)&As[k][ty * 8];
            float4 x1 = *(const float4*)&As[k][ty * 8 + 4];
            float4 bb = *(const float4*)&Bs[k][tx * 4];
            float av[8] = {x0.x, x0.y, x0.z, x0.w, x1.x, x1.y, x1.z, x1.w};
            float bv[4] = {bb.x, bb.y, bb.z, bb.w};
#pragma unroll
            for (int i = 0; i < 8; i++)
#pragma unroll
                for (int j = 0; j < 4; j++) acc[i][j] += av[i] * bv[j];
        }
    }
#pragma unroll
    for (int i = 0; i < 8; i++) {
        float4 o = {acc[i][0], acc[i][1], acc[i][2], acc[i][3]};
        *(float4*)(Cm + (long)(m0 + ty * 8 + i) * 1024 + n0 + tx * 4) = o;
    }
}

// ---------------- hproj[b][c] = sum_h h[b,h] * att_hid2ctx[h,c]  (attT rows) -----
__global__ __launch_bounds__(256) void k_hproj(const float* __restrict__ hT,
                                               const float* __restrict__ attT,
                                               float* __restrict__ hproj) {
    __shared__ float xs[128 * 64];
    int tid = threadIdx.x, lane = tid & 63, w = tid >> 6;
    int c = __builtin_amdgcn_readfirstlane(blockIdx.x * 4 + w);
    float acc = 0.f;
    for (int k0 = 0; k0 < 1024; k0 += 128) {
        __syncthreads();
        const float4* src = (const float4*)(hT + k0 * 64);
        for (int i = tid; i < 2048; i += 256) ((float4*)xs)[i] = src[i];
        __syncthreads();
        const float* wr = attT + (long)c * 1024 + k0;
#pragma unroll 4
        for (int k = 0; k < 128; k++) acc += xs[(k << 6) + lane] * wr[k];
    }
    hproj[lane * 1024 + c] = acc;
}

// ---------------- scores[b][s] = sum_c tanh(ctx_proj[s,b,c]+hproj[b,c])*mlp[c] ---
__global__ __launch_bounds__(256) void k_scores(const float* __restrict__ ctx_proj,
                                                const float* __restrict__ hproj,
                                                const float* __restrict__ mlp,
                                                float* __restrict__ scores) {
    int tid = threadIdx.x, lane = tid & 63, w = tid >> 6;
    int m = blockIdx.x * 4 + w;  // m = s*64 + b
    int b = m & 63, s = m >> 6;
    const float4* cp = (const float4*)(ctx_proj + (long)m * 1024);
    const float4* hp = (const float4*)(hproj + b * 1024);
    const float4* mp = (const float4*)mlp;
    float acc = 0.f;
#pragma unroll
    for (int i = 0; i < 4; i++) {
        int idx = lane + i * 64;
        float4 a = cp[idx], h = hp[idx], mm = mp[idx];
        acc += tanhf(a.x + h.x) * mm.x + tanhf(a.y + h.y) * mm.y +
               tanhf(a.z + h.z) * mm.z + tanhf(a.w + h.w) * mm.w;
    }
#pragma unroll
    for (int off = 32; off; off >>= 1) acc += __shfl_xor(acc, off, 64);
    if (lane == 0) scores[b * 196 + s] = acc;
}

// ---------------- zT[c][b] = sum_s softmax_s(scores[b,:])[s] * ctx[s,b,c] --------
__global__ __launch_bounds__(256) void k_z(const float* __restrict__ scores,
                                           const float* __restrict__ ctx,
                                           float* __restrict__ zT) {
    __shared__ float red[256];
    __shared__ float als[196];
    int tid = threadIdx.x;
    int b = blockIdx.x >> 2, ch = blockIdx.x & 3;
    const float* sc = scores + b * 196;
    float lm = -1e30f;
    for (int s = tid; s < 196; s += 256) lm = fmaxf(lm, sc[s]);
    red[tid] = lm; __syncthreads();
    for (int st = 128; st; st >>= 1) { if (tid < st) red[tid] = fmaxf(red[tid], red[tid + st]); __syncthreads(); }
    float m = red[0]; __syncthreads();
    float ls = 0.f;
    for (int s = tid; s < 196; s += 256) ls += __expf(sc[s] - m);
    red[tid] = ls; __syncthreads();
    for (int st = 128; st; st >>= 1) { if (tid < st) red[tid] += red[tid + st]; __syncthreads(); }
    float inv = 1.f / red[0]; __syncthreads();
    for (int s = tid; s < 196; s += 256) als[s] = __expf(sc[s] - m) * inv;
    __syncthreads();
    int c = ch * 256 + tid;
    float acc = 0.f;
    for (int s = 0; s < 196; s++) acc += als[s] * ctx[(long)(s * 64 + b) * 1024 + c];
    zT[c * 64 + b] = acc;
}

// ---------------- fused GRU cell: hTn[j][b] -------------------------------------
__global__ __launch_bounds__(256) void k_gru(const float* __restrict__ yembT,
                                             const float* __restrict__ zT,
                                             const float* __restrict__ hT,
                                             const float* __restrict__ Wih, const float* __restrict__ bih,
                                             const float* __restrict__ Whh, const float* __restrict__ bhh,
                                             float* __restrict__ hTn, int t) {
    __shared__ float xs[128 * 64];
    int tid = threadIdx.x, lane = tid & 63, w = tid >> 6;
    int j = __builtin_amdgcn_readfirstlane(blockIdx.x * 4 + w);
    float ir = 0, iz = 0, in_ = 0, hr = 0, hz = 0, hn = 0;
    for (int k0 = 0; k0 < 1536; k0 += 128) {
        const float4* src = (k0 < 512) ? (const float4*)(yembT + ((long)t * 512 + k0) * 64)
                                       : (const float4*)(zT + (long)(k0 - 512) * 64);
        __syncthreads();
        for (int i = tid; i < 2048; i += 256) ((float4*)xs)[i] = src[i];
        __syncthreads();
        const float* w0 = Wih + (long)j * 1536 + k0;
        const float* w1 = Wih + (long)(j + 1024) * 1536 + k0;
        const float* w2 = Wih + (long)(j + 2048) * 1536 + k0;
#pragma unroll 4
        for (int k = 0; k < 128; k++) {
            float a = xs[(k << 6) + lane];
            ir += a * w0[k]; iz += a * w1[k]; in_ += a * w2[k];
        }
    }
    for (int k0 = 0; k0 < 1024; k0 += 128) {
        const float4* src = (const float4*)(hT + k0 * 64);
        __syncthreads();
        for (int i = tid; i < 2048; i += 256) ((float4*)xs)[i] = src[i];
        __syncthreads();
        const float* w0 = Whh + (long)j * 1024 + k0;
        const float* w1 = Whh + (long)(j + 1024) * 1024 + k0;
        const float* w2 = Whh + (long)(j + 2048) * 1024 + k0;
#pragma unroll 4
        for (int k = 0; k < 128; k++) {
            float a = xs[(k << 6) + lane];
            hr += a * w0[k]; hz += a * w1[k]; hn += a * w2[k];
        }
    }
    float r = sigmoidf_(ir + bih[j] + hr + bhh[j]);
    float zz = sigmoidf_(iz + bih[1024 + j] + hz + bhh[1024 + j]);
    float n = tanhf(in_ + bih[2048 + j] + r * (hn + bhh[2048 + j]));
    float hp = hT[j * 64 + lane];
    hTn[j * 64 + lane] = (1.f - zz) * n + zz * hp;
}

// ---------------- output head: oT[e][b] = tanh(tanh(ht@h2o^T+b)+y_t+z@octx^T+b) --
__global__ __launch_bounds__(256) void k_out(const float* __restrict__ hT,
                                             const float* __restrict__ zT,
                                             const float* __restrict__ h2oW, const float* __restrict__ h2ob,
                                             const float* __restrict__ octxW, const float* __restrict__ octxb,
                                             const float* __restrict__ yembT, float* __restrict__ oT, int t) {
    __shared__ float xs[128 * 64];
    int tid = threadIdx.x, lane = tid & 63, w = tid >> 6;
    int e = __builtin_amdgcn_readfirstlane(blockIdx.x * 4 + w);
    float a1 = 0.f, a2 = 0.f;
    for (int k0 = 0; k0 < 1024; k0 += 128) {
        __syncthreads();
        const float4* src = (const float4*)(hT + k0 * 64);
        for (int i = tid; i < 2048; i += 256) ((float4*)xs)[i] = src[i];
        __syncthreads();
        const float* wr = h2oW + (long)e * 1024 + k0;
#pragma unroll 4
        for (int k = 0; k < 128; k++) a1 += xs[(k << 6) + lane] * wr[k];
    }
    for (int k0 = 0; k0 < 1024; k0 += 128) {
        __syncthreads();
        const float4* src = (const float4*)(zT + k0 * 64);
        for (int i = tid; i < 2048; i += 256) ((float4*)xs)[i] = src[i];
        __syncthreads();
        const float* wr = octxW + (long)e * 1024 + k0;
#pragma unroll 4
        for (int k = 0; k < 128; k++) a2 += xs[(k << 6) + lane] * wr[k];
    }
    float val = tanhf(a1 + h2ob[e]) + yembT[((long)t * 512 + e) * 64 + lane] + a2 + octxb[e];
    oT[e * 64 + lane] = tanhf(val);
}

// ---------------- vocab logits + online per-lane LSE partials --------------------
__global__ __launch_bounds__(256) void k_vocab(const float* __restrict__ oT,
                                               const float* __restrict__ W,
                                               const float* __restrict__ bias,
                                               float* __restrict__ pm, float* __restrict__ ps) {
    __shared__ float os[128 * 64];
    int tid = threadIdx.x, lane = tid & 63, w = tid >> 6;
    int wid = __builtin_amdgcn_readfirstlane(blockIdx.x * 4 + w);
    int v0 = wid * 16;
    float acc[16];
#pragma unroll
    for (int i = 0; i < 16; i++) acc[i] = 0.f;
    for (int e0 = 0; e0 < 512; e0 += 128) {
        __syncthreads();
        const float4* src = (const float4*)(oT + e0 * 64);
        for (int i = tid; i < 2048; i += 256) ((float4*)os)[i] = src[i];
        __syncthreads();
#pragma unroll 4
        for (int k = 0; k < 128; k++) {
            float a = os[(k << 6) + lane];
#pragma unroll
            for (int vi = 0; vi < 16; vi++) acc[vi] += a * W[(long)(v0 + vi) * 512 + e0 + k];
        }
    }
    float m = -1e30f, ssum = 0.f;
#pragma unroll
    for (int vi = 0; vi < 16; vi++) {
        float x = acc[vi] + bias[v0 + vi];
        float nm = fmaxf(m, x);
        ssum = ssum * __expf(m - nm) + __expf(x - nm);
        m = nm;
    }
    pm[wid * 64 + lane] = m;
    ps[wid * 64 + lane] = ssum;
}

// ---------------- reduce partials -> lse, target logit, accumulate NLL -----------
__global__ __launch_bounds__(256) void k_lse(const float* __restrict__ pm, const float* __restrict__ ps,
                                             const float* __restrict__ oT,
                                             const float* __restrict__ W, const float* __restrict__ bias,
                                             const int* __restrict__ y, float* __restrict__ out, int t) {
    __shared__ float rm[256], rs[256], rd[256];
    int tid = threadIdx.x, b = blockIdx.x;
    float m = -1e30f, s = 0.f;
    for (int i = tid; i < 2000; i += 256) {
        float mi = pm[i * 64 + b], si = ps[i * 64 + b];
        float nm = fmaxf(m, mi);
        s = s * __expf(m - nm) + si * __expf(mi - nm);
        m = nm;
    }
    int tgt = y[(t + 1) * 64 + b];
    const float* wr = W + (long)tgt * 512;
    float d = 0.f;
    for (int e = tid; e < 512; e += 256) d += oT[e * 64 + b] * wr[e];
    rm[tid] = m; rs[tid] = s; rd[tid] = d;
    __syncthreads();
    for (int st = 128; st; st >>= 1) {
        if (tid < st) {
            float m2 = rm[tid + st], s2 = rs[tid + st];
            float nm = fmaxf(rm[tid], m2);
            rs[tid] = rs[tid] * __expf(rm[tid] - nm) + s2 * __expf(m2 - nm);
            rm[tid] = nm;
            rd[tid] += rd[tid + st];
        }
        __syncthreads();
    }
    if (tid == 0) {
        float lse = rm[0] + __logf(rs[0]);
        float lt = rd[0] + bias[tgt];
        float nll = (tgt != 0) ? (lse - lt) : 0.f;
        atomicAdd(out, nll);
    }
}

extern "C" void kernel_launch(void* const* d_in, const int* in_sizes, int n_in,
                              void* d_out, int out_size, void* d_ws, size_t ws_size,
                              hipStream_t stream) {
    const float* ctx     = (const float*)d_in[0];
    const int*   y       = (const int*)d_in[1];
    const float* embW    = (const float*)d_in[2];
    const float* att_c2c = (const float*)d_in[3];
    const float* att_h2c = (const float*)d_in[4];
    const float* mlp     = (const float*)d_in[5];
    const float* Wih     = (const float*)d_in[6];
    const float* bih     = (const float*)d_in[7];
    const float* Whh     = (const float*)d_in[8];
    const float* bhh     = (const float*)d_in[9];
    const float* h2oW    = (const float*)d_in[10];
    const float* h2ob    = (const float*)d_in[11];
    const float* octxW   = (const float*)d_in[12];
    const float* octxb   = (const float*)d_in[13];
    const float* o2pW    = (const float*)d_in[14];
    const float* o2pb    = (const float*)d_in[15];
    float* out = (float*)d_out;

    float* p = (float*)d_ws;
    float* yembT = p;    p += (long)TS_ * E_ * 64;       // 622,592
    float* attT = p;     p += (long)1024 * 1024;         // 1,048,576
    float* ctx_proj = p; p += (long)12544 * 1024;        // 12,845,056
    float* hTa = p;      p += 1024 * 64;
    float* hTb = p;      p += 1024 * 64;
    float* hproj = p;    p += 64 * 1024;
    float* scores = p;   p += 64 * 196;
    float* zT = p;       p += 1024 * 64;
    float* oT = p;       p += 512 * 64;
    float* pm = p;       p += 2000 * 64;
    float* ps = p;       p += 2000 * 64;

    hipMemsetAsync(d_out, 0, sizeof(float), stream);
    hipMemsetAsync(hTa, 0, 1024 * 64 * sizeof(float), stream);

    k_yemb<<<TS_ * 64, 256, 0, stream>>>(y, embW, yembT);
    k_transpose<<<dim3(32, 32), dim3(32, 8), 0, stream>>>(att_h2c, attT);
    k_gemm_ctx<<<dim3(16, 98), 256, 0, stream>>>(ctx, att_c2c, ctx_proj);

    float* hc = hTa;
    float* hn = hTb;
    for (int t = 0; t < TS_; t++) {
        k_hproj<<<256, 256, 0, stream>>>(hc, attT, hproj);
        k_scores<<<3136, 256, 0, stream>>>(ctx_proj, hproj, mlp, scores);
        k_z<<<256, 256, 0, stream>>>(scores, ctx, zT);
        k_gru<<<256, 256, 0, stream>>>(yembT, zT, hc, Wih, bih, Whh, bhh, hn, t);
        k_out<<<128, 256, 0, stream>>>(hn, zT, h2oW, h2ob, octxW, octxb, yembT, oT, t);
        k_vocab<<<500, 256, 0, stream>>>(oT, o2pW, o2pb, pm, ps);
        k_lse<<<64, 256, 0, stream>>>(pm, ps, oT, o2pW, o2pb, y, out, t);
        float* tmp = hc; hc = hn; hn = tmp;
    }
}

// Round 2
// 2641.299 us; speedup vs baseline: 3.2273x; 3.2273x over previous
//
#include <hip/hip_runtime.h>
#include <math.h>

#define TS_ 19   // T-1 decode steps

typedef float f32x4 __attribute__((ext_vector_type(4)));
typedef short s16x8 __attribute__((ext_vector_type(8)));

__device__ __forceinline__ float sigmoidf_(float x) { return 1.f / (1.f + __expf(-x)); }

__device__ __forceinline__ float fast_tanh(float x) {
    float ax = fabsf(x);
    float e = __expf(-2.f * ax);
    float r = (1.f - e) * __builtin_amdgcn_rcpf(1.f + e);
    return copysignf(r, x);
}

__device__ __forceinline__ unsigned short f2b(float x) {
    union { float f; unsigned u; } v; v.f = x;
    unsigned r = v.u + 0x7fffu + ((v.u >> 16) & 1u);
    return (unsigned short)(r >> 16);
}
__device__ __forceinline__ float b2f(unsigned short u) {
    union { unsigned u; float f; } v; v.u = ((unsigned)u) << 16; return v.f;
}

#define MFMA(a, b, c) __builtin_amdgcn_mfma_f32_16x16x32_bf16((a), (b), (c), 0, 0, 0)

// ---------------- fp32 -> bf16 flat convert ----------------
__global__ __launch_bounds__(256) void k_cvt(const float* __restrict__ in,
                                             unsigned short* __restrict__ out, long n) {
    long i = ((long)blockIdx.x * 256 + threadIdx.x) * 4;
    long stride = (long)gridDim.x * 1024;
    for (; i < n; i += stride) {
        float4 v = *(const float4*)(in + i);
        ushort4 o = { f2b(v.x), f2b(v.y), f2b(v.z), f2b(v.w) };
        *(ushort4*)(out + i) = o;
    }
}

// ---------------- 1024x1024 transpose + cvt ----------------
__global__ void k_tcvt(const float* __restrict__ in, unsigned short* __restrict__ out) {
    __shared__ float tile[32][33];
    int bx = blockIdx.x * 32, by = blockIdx.y * 32;
    int x = threadIdx.x, y0 = threadIdx.y;
    for (int yy = y0; yy < 32; yy += 8) tile[yy][x] = in[(by + yy) * 1024 + bx + x];
    __syncthreads();
    for (int yy = y0; yy < 32; yy += 8) out[(bx + yy) * 1024 + by + x] = f2b(tile[x][yy]);
}

// ---------------- embedding gather -> bf16 [t][b][512] ----------------
__global__ __launch_bounds__(256) void k_yemb(const int* __restrict__ y,
                                              const float* __restrict__ embW,
                                              unsigned short* __restrict__ yembbf) {
    int t = blockIdx.x >> 6, b = blockIdx.x & 63;
    int row = y[t * 64 + b];
    const float* src = embW + (long)row * 512;
    unsigned short* dst = yembbf + ((long)(t * 64 + b) << 9);
    for (int e = threadIdx.x; e < 512; e += 256) dst[e] = f2b(src[e]);
}

// ---------------- ctx_projbf = ctxbf @ c2cT^T : [12544][1024] bf16 out ----------
// block = 4 waves; wave w handles m-tile (16 rows), 4 n-subtiles (64 cols/block)
__global__ __launch_bounds__(256) void k_gemmctx(const unsigned short* __restrict__ A,
                                                 const unsigned short* __restrict__ Bt,
                                                 unsigned short* __restrict__ Cb) {
    int tid = threadIdx.x, lane = tid & 63, w = tid >> 6;
    int mblk = blockIdx.x % 196, nblk = blockIdx.x / 196;
    int m0 = mblk * 64 + w * 16;
    int n0 = nblk * 64;
    int mr = lane & 15, kb = lane >> 4;
    const unsigned short* ap = A + (long)(m0 + mr) * 1024 + kb * 8;
    f32x4 acc[4];
#pragma unroll
    for (int i = 0; i < 4; i++) acc[i] = (f32x4){0.f, 0.f, 0.f, 0.f};
#pragma unroll 4
    for (int k0 = 0; k0 < 1024; k0 += 32) {
        s16x8 a = *(const s16x8*)(ap + k0);
#pragma unroll
        for (int nt = 0; nt < 4; nt++) {
            s16x8 b = *(const s16x8*)(Bt + (long)(n0 + nt * 16 + mr) * 1024 + k0 + kb * 8);
            acc[nt] = MFMA(a, b, acc[nt]);
        }
    }
#pragma unroll
    for (int nt = 0; nt < 4; nt++)
#pragma unroll
        for (int j = 0; j < 4; j++)
            Cb[(long)(m0 + kb * 4 + j) * 1024 + n0 + nt * 16 + mr] = f2b(acc[nt][j]);
}

// ---------------- hproj[64][1024] f32 = hbf @ attbf^T ----------------
__global__ __launch_bounds__(256) void k_hproj(const unsigned short* __restrict__ hbf,
                                               const unsigned short* __restrict__ attbf,
                                               float* __restrict__ hproj) {
    int tid = threadIdx.x, lane = tid & 63, w = tid >> 6;
    int n0 = blockIdx.x * 16;
    int m0 = w * 16;
    int mr = lane & 15, kb = lane >> 4;
    const unsigned short* ap = hbf + (long)(m0 + mr) * 1024 + kb * 8;
    const unsigned short* bp = attbf + (long)(n0 + mr) * 1024 + kb * 8;
    f32x4 acc = (f32x4){0.f, 0.f, 0.f, 0.f};
#pragma unroll 4
    for (int k0 = 0; k0 < 1024; k0 += 32) {
        s16x8 a = *(const s16x8*)(ap + k0);
        s16x8 b = *(const s16x8*)(bp + k0);
        acc = MFMA(a, b, acc);
    }
#pragma unroll
    for (int j = 0; j < 4; j++)
        hproj[(long)(m0 + kb * 4 + j) * 1024 + n0 + mr] = acc[j];
}

// ---------------- scores[b][s] = sum_c tanh(cp + hproj)*mlp ----------------
__global__ __launch_bounds__(256) void k_scores(const unsigned short* __restrict__ cpb,
                                                const float* __restrict__ hproj,
                                                const float* __restrict__ mlp,
                                                float* __restrict__ scores) {
    int tid = threadIdx.x, lane = tid & 63, w = tid >> 6;
    int m = blockIdx.x * 4 + w;
    int b = m & 63, s = m >> 6;
    const unsigned short* cp = cpb + (long)m * 1024;
    float acc = 0.f;
#pragma unroll
    for (int i = 0; i < 2; i++) {
        int e0 = i * 512 + lane * 8;
        s16x8 cv = *(const s16x8*)(cp + e0);
        float4 h0 = *(const float4*)(hproj + b * 1024 + e0);
        float4 h1 = *(const float4*)(hproj + b * 1024 + e0 + 4);
        float4 m0v = *(const float4*)(mlp + e0);
        float4 m1v = *(const float4*)(mlp + e0 + 4);
        float hv[8] = {h0.x, h0.y, h0.z, h0.w, h1.x, h1.y, h1.z, h1.w};
        float mv[8] = {m0v.x, m0v.y, m0v.z, m0v.w, m1v.x, m1v.y, m1v.z, m1v.w};
#pragma unroll
        for (int j = 0; j < 8; j++)
            acc += fast_tanh(b2f((unsigned short)cv[j]) + hv[j]) * mv[j];
    }
#pragma unroll
    for (int off = 32; off; off >>= 1) acc += __shfl_xor(acc, off, 64);
    if (lane == 0) scores[b * 196 + s] = acc;
}

// ---------------- softmax + z: zbf[b][1024] ----------------
__global__ __launch_bounds__(256) void k_z(const float* __restrict__ scores,
                                           const unsigned short* __restrict__ ctxbf,
                                           unsigned short* __restrict__ zbf) {
    __shared__ float red[256];
    __shared__ float als[196];
    int tid = threadIdx.x, b = blockIdx.x;
    const float* sc = scores + b * 196;
    float lm = -1e30f;
    for (int s = tid; s < 196; s += 256) lm = fmaxf(lm, sc[s]);
    red[tid] = lm; __syncthreads();
    for (int st = 128; st; st >>= 1) { if (tid < st) red[tid] = fmaxf(red[tid], red[tid + st]); __syncthreads(); }
    float m = red[0]; __syncthreads();
    float ls = 0.f;
    for (int s = tid; s < 196; s += 256) ls += __expf(sc[s] - m);
    red[tid] = ls; __syncthreads();
    for (int st = 128; st; st >>= 1) { if (tid < st) red[tid] += red[tid + st]; __syncthreads(); }
    float inv = 1.f / red[0]; __syncthreads();
    for (int s = tid; s < 196; s += 256) als[s] = __expf(sc[s] - m) * inv;
    __syncthreads();
    float a0 = 0.f, a1 = 0.f, a2 = 0.f, a3 = 0.f;
    const unsigned short* cb = ctxbf + (long)b * 1024 + tid * 4;
    for (int s = 0; s < 196; s++) {
        ushort4 v = *(const ushort4*)(cb + (long)s * 65536);
        float al = als[s];
        a0 += al * b2f(v.x); a1 += al * b2f(v.y); a2 += al * b2f(v.z); a3 += al * b2f(v.w);
    }
    ushort4 o = { f2b(a0), f2b(a1), f2b(a2), f2b(a3) };
    *(ushort4*)(zbf + (long)b * 1024 + tid * 4) = o;
}

// ---------------- GRU cell via MFMA ----------------
__global__ __launch_bounds__(256) void k_gru(const unsigned short* __restrict__ yembbf,
                                             const unsigned short* __restrict__ zbf,
                                             const unsigned short* __restrict__ hbf,
                                             const float* __restrict__ hf32,
                                             const unsigned short* __restrict__ Wihbf,
                                             const float* __restrict__ bih,
                                             const unsigned short* __restrict__ Whhbf,
                                             const float* __restrict__ bhh,
                                             float* __restrict__ hf32n,
                                             unsigned short* __restrict__ hbfn, int t) {
    int tid = threadIdx.x, lane = tid & 63, w = tid >> 6;
    int n0 = blockIdx.x * 16;
    int m0 = w * 16;
    int mr = lane & 15, kb = lane >> 4;
    f32x4 a_r = (f32x4){0.f,0.f,0.f,0.f}, a_z = a_r, a_in = a_r, a_hn = a_r;

    const unsigned short* ye = yembbf + ((long)(t * 64 + m0 + mr) << 9) + kb * 8;
    const unsigned short* zp = zbf + (long)(m0 + mr) * 1024 + kb * 8;
    const unsigned short* wr = Wihbf + (long)(n0 + mr) * 1536 + kb * 8;
#pragma unroll 4
    for (int k0 = 0; k0 < 512; k0 += 32) {
        s16x8 a = *(const s16x8*)(ye + k0);
        s16x8 br = *(const s16x8*)(wr + k0);
        s16x8 bz = *(const s16x8*)(wr + (long)1024 * 1536 + k0);
        s16x8 bn = *(const s16x8*)(wr + (long)2048 * 1536 + k0);
        a_r = MFMA(a, br, a_r); a_z = MFMA(a, bz, a_z); a_in = MFMA(a, bn, a_in);
    }
#pragma unroll 4
    for (int k0 = 512; k0 < 1536; k0 += 32) {
        s16x8 a = *(const s16x8*)(zp + k0 - 512);
        s16x8 br = *(const s16x8*)(wr + k0);
        s16x8 bz = *(const s16x8*)(wr + (long)1024 * 1536 + k0);
        s16x8 bn = *(const s16x8*)(wr + (long)2048 * 1536 + k0);
        a_r = MFMA(a, br, a_r); a_z = MFMA(a, bz, a_z); a_in = MFMA(a, bn, a_in);
    }
    const unsigned short* hp = hbf + (long)(m0 + mr) * 1024 + kb * 8;
    const unsigned short* wh = Whhbf + (long)(n0 + mr) * 1024 + kb * 8;
#pragma unroll 4
    for (int k0 = 0; k0 < 1024; k0 += 32) {
        s16x8 a = *(const s16x8*)(hp + k0);
        s16x8 br = *(const s16x8*)(wh + k0);
        s16x8 bz = *(const s16x8*)(wh + (long)1024 * 1024 + k0);
        s16x8 bn = *(const s16x8*)(wh + (long)2048 * 1024 + k0);
        a_r = MFMA(a, br, a_r); a_z = MFMA(a, bz, a_z); a_hn = MFMA(a, bn, a_hn);
    }
    int jc = n0 + mr;
    float br_ = bih[jc] + bhh[jc];
    float bz_ = bih[1024 + jc] + bhh[1024 + jc];
    float bin_ = bih[2048 + jc], bhn_ = bhh[2048 + jc];
#pragma unroll
    for (int j = 0; j < 4; j++) {
        int b = m0 + kb * 4 + j;
        float r = sigmoidf_(a_r[j] + br_);
        float zz = sigmoidf_(a_z[j] + bz_);
        float n = fast_tanh(a_in[j] + bin_ + r * (a_hn[j] + bhn_));
        float hprev = hf32[(long)b * 1024 + jc];
        float hv = (1.f - zz) * n + zz * hprev;
        hf32n[(long)b * 1024 + jc] = hv;
        hbfn[(long)b * 1024 + jc] = f2b(hv);
    }
}

// ---------------- output head via MFMA: obf[b][512] ----------------
__global__ __launch_bounds__(256) void k_out(const unsigned short* __restrict__ hbf,
                                             const unsigned short* __restrict__ zbf,
                                             const unsigned short* __restrict__ h2obf,
                                             const float* __restrict__ h2ob,
                                             const unsigned short* __restrict__ octxbf,
                                             const float* __restrict__ octxb,
                                             const unsigned short* __restrict__ yembbf,
                                             unsigned short* __restrict__ obf, int t) {
    int tid = threadIdx.x, lane = tid & 63, w = tid >> 6;
    int n0 = blockIdx.x * 16;
    int m0 = w * 16;
    int mr = lane & 15, kb = lane >> 4;
    const unsigned short* ah = hbf + (long)(m0 + mr) * 1024 + kb * 8;
    const unsigned short* az = zbf + (long)(m0 + mr) * 1024 + kb * 8;
    const unsigned short* b1p = h2obf + (long)(n0 + mr) * 1024 + kb * 8;
    const unsigned short* b2p = octxbf + (long)(n0 + mr) * 1024 + kb * 8;
    f32x4 a1 = (f32x4){0.f,0.f,0.f,0.f}, a2 = a1;
#pragma unroll 4
    for (int k0 = 0; k0 < 1024; k0 += 32) {
        a1 = MFMA(*(const s16x8*)(ah + k0), *(const s16x8*)(b1p + k0), a1);
        a2 = MFMA(*(const s16x8*)(az + k0), *(const s16x8*)(b2p + k0), a2);
    }
    int e = n0 + mr;
    float b1v = h2ob[e], b2v = octxb[e];
#pragma unroll
    for (int j = 0; j < 4; j++) {
        int b = m0 + kb * 4 + j;
        float ye = b2f(yembbf[((long)(t * 64 + b) << 9) + e]);
        float val = fast_tanh(a1[j] + b1v) + ye + a2[j] + b2v;
        obf[(long)b * 512 + e] = f2b(fast_tanh(val));
    }
}

// ---------------- vocab logits via MFMA + per-wave LSE partials ----------------
__global__ __launch_bounds__(256) void k_vocab(const unsigned short* __restrict__ obf,
                                               const unsigned short* __restrict__ o2pbf,
                                               const float* __restrict__ bias,
                                               float* __restrict__ pm, float* __restrict__ ps) {
    int tid = threadIdx.x, lane = tid & 63, w = tid >> 6;
    int wid = blockIdx.x * 4 + w;
    int v0 = wid * 16;
    int mr = lane & 15, kb = lane >> 4;
    const unsigned short* bp = o2pbf + (long)(v0 + mr) * 512 + kb * 8;
    const unsigned short* ap = obf + (long)mr * 512 + kb * 8;
    f32x4 acc[4];
#pragma unroll
    for (int i = 0; i < 4; i++) acc[i] = (f32x4){0.f, 0.f, 0.f, 0.f};
#pragma unroll 2
    for (int k0 = 0; k0 < 512; k0 += 32) {
        s16x8 b = *(const s16x8*)(bp + k0);
#pragma unroll
        for (int mt = 0; mt < 4; mt++) {
            s16x8 a = *(const s16x8*)(ap + (long)mt * 16 * 512 + k0);
            acc[mt] = MFMA(a, b, acc[mt]);
        }
    }
    float bv = bias[v0 + mr];
#pragma unroll
    for (int mt = 0; mt < 4; mt++)
#pragma unroll
        for (int j = 0; j < 4; j++) {
            float x = acc[mt][j] + bv;
            float mm = x;
            mm = fmaxf(mm, __shfl_xor(mm, 1, 64));
            mm = fmaxf(mm, __shfl_xor(mm, 2, 64));
            mm = fmaxf(mm, __shfl_xor(mm, 4, 64));
            mm = fmaxf(mm, __shfl_xor(mm, 8, 64));
            float ee = __expf(x - mm);
            ee += __shfl_xor(ee, 1, 64);
            ee += __shfl_xor(ee, 2, 64);
            ee += __shfl_xor(ee, 4, 64);
            ee += __shfl_xor(ee, 8, 64);
            if (mr == 0) {
                int b = mt * 16 + kb * 4 + j;
                pm[(long)wid * 64 + b] = mm;
                ps[(long)wid * 64 + b] = ee;
            }
        }
}

// ---------------- reduce partials -> lse, target logit, accumulate NLL ----------
__global__ __launch_bounds__(256) void k_lse(const float* __restrict__ pm, const float* __restrict__ ps,
                                             const unsigned short* __restrict__ obf,
                                             const float* __restrict__ W, const float* __restrict__ bias,
                                             const int* __restrict__ y, float* __restrict__ out, int t) {
    __shared__ float rm[256], rs[256], rd[256];
    int tid = threadIdx.x, b = blockIdx.x;
    float m = -1e30f, s = 0.f;
    for (int i = tid; i < 2000; i += 256) {
        float mi = pm[(long)i * 64 + b], si = ps[(long)i * 64 + b];
        float nm = fmaxf(m, mi);
        s = s * __expf(m - nm) + si * __expf(mi - nm);
        m = nm;
    }
    int tgt = y[(t + 1) * 64 + b];
    const float* wr = W + (long)tgt * 512;
    float d = 0.f;
    for (int e = tid; e < 512; e += 256) d += b2f(obf[(long)b * 512 + e]) * wr[e];
    rm[tid] = m; rs[tid] = s; rd[tid] = d;
    __syncthreads();
    for (int st = 128; st; st >>= 1) {
        if (tid < st) {
            float m2 = rm[tid + st], s2 = rs[tid + st];
            float nm = fmaxf(rm[tid], m2);
            rs[tid] = rs[tid] * __expf(rm[tid] - nm) + s2 * __expf(m2 - nm);
            rm[tid] = nm;
            rd[tid] += rd[tid + st];
        }
        __syncthreads();
    }
    if (tid == 0) {
        float lse = rm[0] + __logf(rs[0]);
        float lt = rd[0] + bias[tgt];
        float nll = (tgt != 0) ? (lse - lt) : 0.f;
        atomicAdd(out, nll);
    }
}

extern "C" void kernel_launch(void* const* d_in, const int* in_sizes, int n_in,
                              void* d_out, int out_size, void* d_ws, size_t ws_size,
                              hipStream_t stream) {
    const float* ctx     = (const float*)d_in[0];
    const int*   y       = (const int*)d_in[1];
    const float* embW    = (const float*)d_in[2];
    const float* att_c2c = (const float*)d_in[3];
    const float* att_h2c = (const float*)d_in[4];
    const float* mlp     = (const float*)d_in[5];
    const float* Wih     = (const float*)d_in[6];
    const float* bih     = (const float*)d_in[7];
    const float* Whh     = (const float*)d_in[8];
    const float* bhh     = (const float*)d_in[9];
    const float* h2oW    = (const float*)d_in[10];
    const float* h2ob    = (const float*)d_in[11];
    const float* octxW   = (const float*)d_in[12];
    const float* octxb   = (const float*)d_in[13];
    const float* o2pW    = (const float*)d_in[14];
    const float* o2pb    = (const float*)d_in[15];
    float* out = (float*)d_out;

    char* base = (char*)d_ws;
    unsigned short* ctxbf  = (unsigned short*)base;            base += (long)12845056 * 2;
    unsigned short* cpbf   = (unsigned short*)base;            base += (long)12845056 * 2;
    unsigned short* c2cT   = (unsigned short*)base;            base += (long)1048576 * 2;
    unsigned short* attbf  = (unsigned short*)base;            base += (long)1048576 * 2;
    unsigned short* Wihbf  = (unsigned short*)base;            base += (long)4718592 * 2;
    unsigned short* Whhbf  = (unsigned short*)base;            base += (long)3145728 * 2;
    unsigned short* h2obf  = (unsigned short*)base;            base += (long)524288 * 2;
    unsigned short* octxbf = (unsigned short*)base;            base += (long)524288 * 2;
    unsigned short* o2pbf  = (unsigned short*)base;            base += (long)16384000 * 2;
    unsigned short* yembbf = (unsigned short*)base;            base += (long)622592 * 2;
    unsigned short* zbf    = (unsigned short*)base;            base += (long)65536 * 2;
    unsigned short* obf    = (unsigned short*)base;            base += (long)32768 * 2;
    unsigned short* hbfa   = (unsigned short*)base;            base += (long)65536 * 2;
    unsigned short* hbfb   = (unsigned short*)base;            base += (long)65536 * 2;
    float* hf32a = (float*)base;  base += (long)65536 * 4;
    float* hf32b = (float*)base;  base += (long)65536 * 4;
    float* hproj = (float*)base;  base += (long)65536 * 4;
    float* scores = (float*)base; base += (long)12544 * 4;
    float* pm = (float*)base;     base += (long)128000 * 4;
    float* ps = (float*)base;     base += (long)128000 * 4;

    hipMemsetAsync(d_out, 0, sizeof(float), stream);
    hipMemsetAsync(hf32a, 0, 65536 * sizeof(float), stream);
    hipMemsetAsync(hbfa, 0, 65536 * sizeof(unsigned short), stream);

    // one-time conversions
    k_cvt<<<2048, 256, 0, stream>>>(ctx, ctxbf, (long)12845056);
    k_cvt<<<2048, 256, 0, stream>>>(Wih, Wihbf, (long)4718592);
    k_cvt<<<2048, 256, 0, stream>>>(Whh, Whhbf, (long)3145728);
    k_cvt<<<1024, 256, 0, stream>>>(h2oW, h2obf, (long)524288);
    k_cvt<<<1024, 256, 0, stream>>>(octxW, octxbf, (long)524288);
    k_cvt<<<2048, 256, 0, stream>>>(o2pW, o2pbf, (long)16384000);
    k_tcvt<<<dim3(32, 32), dim3(32, 8), 0, stream>>>(att_c2c, c2cT);
    k_tcvt<<<dim3(32, 32), dim3(32, 8), 0, stream>>>(att_h2c, attbf);
    k_yemb<<<TS_ * 64, 256, 0, stream>>>(y, embW, yembbf);
    k_gemmctx<<<3136, 256, 0, stream>>>(ctxbf, c2cT, cpbf);

    unsigned short* hbc = hbfa; unsigned short* hbn = hbfb;
    float* hfc = hf32a; float* hfn = hf32b;
    for (int t = 0; t < TS_; t++) {
        k_hproj<<<64, 256, 0, stream>>>(hbc, attbf, hproj);
        k_scores<<<3136, 256, 0, stream>>>(cpbf, hproj, mlp, scores);
        k_z<<<64, 256, 0, stream>>>(scores, ctxbf, zbf);
        k_gru<<<64, 256, 0, stream>>>(yembbf, zbf, hbc, hfc, Wihbf, bih, Whhbf, bhh, hfn, hbn, t);
        k_out<<<32, 256, 0, stream>>>(hbn, zbf, h2obf, h2ob, octxbf, octxb, yembbf, obf, t);
        k_vocab<<<500, 256, 0, stream>>>(obf, o2pbf, o2pb, pm, ps);
        k_lse<<<64, 256, 0, stream>>>(pm, ps, obf, o2pW, o2pb, y, out, t);
        unsigned short* tb = hbc; hbc = hbn; hbn = tb;
        float* tf = hfc; hfc = hfn; hfn = tf;
    }
}

// Round 3
// 2026.268 us; speedup vs baseline: 4.2069x; 1.3035x over previous
//
#include <hip/hip_runtime.h>
#include <math.h>

#define TS_ 19   // T-1 decode steps

typedef float f32x4 __attribute__((ext_vector_type(4)));
typedef short s16x8 __attribute__((ext_vector_type(8)));
typedef short s16x4 __attribute__((ext_vector_type(4)));

__device__ __forceinline__ float sigmoidf_(float x) { return 1.f / (1.f + __expf(-x)); }

__device__ __forceinline__ float fast_tanh(float x) {
    float ax = fabsf(x);
    float e = __expf(-2.f * ax);
    float r = (1.f - e) * __builtin_amdgcn_rcpf(1.f + e);
    return copysignf(r, x);
}

__device__ __forceinline__ unsigned short f2b(float x) {
    union { float f; unsigned u; } v; v.f = x;
    unsigned r = v.u + 0x7fffu + ((v.u >> 16) & 1u);
    return (unsigned short)(r >> 16);
}
__device__ __forceinline__ float b2f(unsigned short u) {
    union { unsigned u; float f; } v; v.u = ((unsigned)u) << 16; return v.f;
}

#define MFMA(a, b, c) __builtin_amdgcn_mfma_f32_16x16x32_bf16((a), (b), (c), 0, 0, 0)

// ---------------- fp32 -> bf16 flat convert (grid-stride) ----------------
__global__ __launch_bounds__(256) void k_cvt(const float* __restrict__ in,
                                             unsigned short* __restrict__ out, long n) {
    long i = ((long)blockIdx.x * 256 + threadIdx.x) * 4;
    long stride = (long)gridDim.x * 1024;
    for (; i < n; i += stride) {
        float4 v = *(const float4*)(in + i);
        ushort4 o = { f2b(v.x), f2b(v.y), f2b(v.z), f2b(v.w) };
        *(ushort4*)(out + i) = o;
    }
}

// ---------------- 1024x1024 transpose + cvt ----------------
__global__ void k_tcvt(const float* __restrict__ in, unsigned short* __restrict__ out) {
    __shared__ float tile[32][33];
    int bx = blockIdx.x * 32, by = blockIdx.y * 32;
    int x = threadIdx.x, y0 = threadIdx.y;
    for (int yy = y0; yy < 32; yy += 8) tile[yy][x] = in[(by + yy) * 1024 + bx + x];
    __syncthreads();
    for (int yy = y0; yy < 32; yy += 8) out[(bx + yy) * 1024 + by + x] = f2b(tile[x][yy]);
}

// ---------------- embedding gather -> xc slot0 bf16 ----------------
__global__ __launch_bounds__(256) void k_yemb(const int* __restrict__ y,
                                              const float* __restrict__ embW,
                                              unsigned short* __restrict__ xc) {
    int t = blockIdx.x >> 6, b = blockIdx.x & 63;
    int row = y[t * 64 + b];
    const float* src = embW + (long)row * 512;
    unsigned short* dst = xc + (long)(t * 64 + b) * 2560;
    for (int e = threadIdx.x; e < 512; e += 256) dst[e] = f2b(src[e]);
}

// ---------------- packed gate-weight build: Wg (bf16) ----------------
// rows 0..2047   : r/z gates, K=2560 = [Wih row n | Whh row n]
// rows 2048..3071: i_n gate,  K=1536 = Wih row n
// rows 3072..4095: h_n gate,  K=1024 = Whh row (n-1024)
__global__ __launch_bounds__(256) void k_prepw(const float* __restrict__ Wih,
                                               const float* __restrict__ Whh,
                                               unsigned short* __restrict__ Wg) {
    int n = blockIdx.x, tid = threadIdx.x;
    int cl = n >> 10;
    if (cl < 2) {
        long base = (long)n * 2560;
        const float* wi = Wih + (long)n * 1536;
        const float* wh = Whh + (long)n * 1024;
        for (int k = tid; k < 1536; k += 256) Wg[base + k] = f2b(wi[k]);
        for (int k = tid; k < 1024; k += 256) Wg[base + 1536 + k] = f2b(wh[k]);
    } else if (cl == 2) {
        long base = 5242880L + (long)(n - 2048) * 1536;
        const float* wi = Wih + (long)n * 1536;
        for (int k = tid; k < 1536; k += 256) Wg[base + k] = f2b(wi[k]);
    } else {
        long base = 6815744L + (long)(n - 3072) * 1024;
        const float* wh = Whh + (long)(n - 1024) * 1024;
        for (int k = tid; k < 1024; k += 256) Wg[base + k] = f2b(wh[k]);
    }
}

// ---------------- ctx_proj GEMM: [12544,1024]f32 x [1024,1024]bf16^T -> bf16 ----
// 128x64 tile, BK=64, LDS-staged with XOR-swizzled quads, XCD-swizzled grid.
__global__ __launch_bounds__(256) void k_gemm(const float* __restrict__ A,
                                              const unsigned short* __restrict__ Bt,
                                              unsigned short* __restrict__ Cb) {
    __shared__ short lds[12288];  // A: [0,8192) shorts (128x64), B: [8192,12288) (64x64)
    int tid = threadIdx.x, lane = tid & 63, w = tid >> 6;
    int sw = (blockIdx.x & 7) * 196 + (blockIdx.x >> 3);   // XCD swizzle (1568 = 8*196)
    int mblk = sw >> 4, nblk = sw & 15;
    long m0 = (long)mblk * 128, n0 = (long)nblk * 64;
    int wr = w >> 1, wc = w & 1;
    int mr = lane & 15, kb = lane >> 4;
    int ar = tid >> 4, ac = tid & 15;      // A staging: row ar+16*it, f32x4 chunk ac
    int aq = ((ac >> 1) ^ (ar & 7)) * 8 + (ac & 1) * 4;
    int br_ = tid >> 2, bq = tid & 3;      // B staging: row br_, chunks bq*2+i

    f32x4 acc[4][2];
#pragma unroll
    for (int i = 0; i < 4; i++)
#pragma unroll
        for (int j = 0; j < 2; j++) acc[i][j] = (f32x4){0.f, 0.f, 0.f, 0.f};

    for (int kt = 0; kt < 16; kt++) {
        int k0 = kt * 64;
        float4 av[8];
#pragma unroll
        for (int it = 0; it < 8; it++)
            av[it] = *(const float4*)(A + (m0 + ar + it * 16) * 1024 + k0 + ac * 4);
        s16x8 bv[2];
#pragma unroll
        for (int i = 0; i < 2; i++)
            bv[i] = *(const s16x8*)(Bt + (n0 + br_) * 1024 + k0 + (bq * 2 + i) * 8);
        __syncthreads();
#pragma unroll
        for (int it = 0; it < 8; it++) {
            s16x4 pk = { (short)f2b(av[it].x), (short)f2b(av[it].y),
                         (short)f2b(av[it].z), (short)f2b(av[it].w) };
            *(s16x4*)&lds[(ar + it * 16) * 64 + aq] = pk;
        }
#pragma unroll
        for (int i = 0; i < 2; i++) {
            int c2 = bq * 2 + i;
            *(s16x8*)&lds[8192 + br_ * 64 + ((c2 ^ (br_ & 7)) * 8)] = bv[i];
        }
        __syncthreads();
#pragma unroll
        for (int ks = 0; ks < 2; ks++) {
            int xq = ((ks * 4 + kb) ^ (mr & 7)) * 8;
            s16x8 af[4], bf[2];
#pragma unroll
            for (int mt = 0; mt < 4; mt++)
                af[mt] = *(s16x8*)&lds[(wr * 64 + mt * 16 + mr) * 64 + xq];
#pragma unroll
            for (int nt = 0; nt < 2; nt++)
                bf[nt] = *(s16x8*)&lds[8192 + (wc * 32 + nt * 16 + mr) * 64 + xq];
#pragma unroll
            for (int mt = 0; mt < 4; mt++)
#pragma unroll
                for (int nt = 0; nt < 2; nt++)
                    acc[mt][nt] = MFMA(af[mt], bf[nt], acc[mt][nt]);
        }
    }
#pragma unroll
    for (int mt = 0; mt < 4; mt++)
#pragma unroll
        for (int nt = 0; nt < 2; nt++)
#pragma unroll
            for (int jj = 0; jj < 4; jj++)
                Cb[(m0 + wr * 64 + mt * 16 + kb * 4 + jj) * 1024 +
                   n0 + wc * 32 + nt * 16 + mr] = f2b(acc[mt][nt][jj]);
}

// ---------------- hproj parts: hpp[kc][b][n] = (h @ attT)_Khalf ----------------
__global__ __launch_bounds__(256) void k_hproj(const unsigned short* __restrict__ hbf,
                                               const unsigned short* __restrict__ attbf,
                                               float* __restrict__ hpp) {
    int tid = threadIdx.x, lane = tid & 63, w = tid >> 6;
    int vn0 = (blockIdx.x >> 1) * 16, kc = blockIdx.x & 1;
    int m0 = w * 16, mr = lane & 15, kb = lane >> 4;
    const unsigned short* ap = hbf + (long)(m0 + mr) * 1024 + kc * 512 + kb * 8;
    const unsigned short* bp = attbf + (long)(vn0 + mr) * 1024 + kc * 512 + kb * 8;
    f32x4 acc = (f32x4){0.f, 0.f, 0.f, 0.f};
#pragma unroll 4
    for (int k0 = 0; k0 < 512; k0 += 32)
        acc = MFMA(*(const s16x8*)(ap + k0), *(const s16x8*)(bp + k0), acc);
#pragma unroll
    for (int j = 0; j < 4; j++)
        hpp[(long)kc * 65536 + (long)(m0 + kb * 4 + j) * 1024 + vn0 + mr] = acc[j];
}

// ---------------- scores[b][s] = sum_c tanh(cp + hproj)*mlp ----------------
// block: one b, 4 s values (one per wave); hproj parts summed into LDS once.
__global__ __launch_bounds__(256) void k_scores(const unsigned short* __restrict__ cpb,
                                                const float* __restrict__ hpp,
                                                const float* __restrict__ mlp,
                                                float* __restrict__ scores) {
    __shared__ float hp[1024];
    int tid = threadIdx.x, lane = tid & 63, w = tid >> 6;
    int b = blockIdx.x / 49, s0 = (blockIdx.x % 49) * 4;
    for (int e = tid; e < 1024; e += 256)
        hp[e] = hpp[(long)b * 1024 + e] + hpp[65536 + (long)b * 1024 + e];
    __syncthreads();
    int s = s0 + w;
    const unsigned short* cp = cpb + (long)(s * 64 + b) * 1024;
    float acc = 0.f;
#pragma unroll
    for (int i = 0; i < 2; i++) {
        int e0 = i * 512 + lane * 8;
        s16x8 cv = *(const s16x8*)(cp + e0);
        float4 m0v = *(const float4*)(mlp + e0);
        float4 m1v = *(const float4*)(mlp + e0 + 4);
        float mv[8] = {m0v.x, m0v.y, m0v.z, m0v.w, m1v.x, m1v.y, m1v.z, m1v.w};
#pragma unroll
        for (int j = 0; j < 8; j++)
            acc += fast_tanh(b2f((unsigned short)cv[j]) + hp[e0 + j]) * mv[j];
    }
#pragma unroll
    for (int off = 32; off; off >>= 1) acc += __shfl_xor(acc, off, 64);
    if (lane == 0) scores[b * 196 + s] = acc;
}

// ---------------- softmax + z -> xc z-slot (bf16) ----------------
__global__ __launch_bounds__(256) void k_z(const float* __restrict__ scores,
                                           const float* __restrict__ ctx,
                                           unsigned short* __restrict__ xc, int t) {
    __shared__ float red[256];
    __shared__ float als[196];
    int tid = threadIdx.x, b = blockIdx.x >> 1, half = blockIdx.x & 1;
    const float* sc = scores + b * 196;
    float lm = -1e30f;
    for (int s = tid; s < 196; s += 256) lm = fmaxf(lm, sc[s]);
    red[tid] = lm; __syncthreads();
    for (int st = 128; st; st >>= 1) { if (tid < st) red[tid] = fmaxf(red[tid], red[tid + st]); __syncthreads(); }
    float m = red[0]; __syncthreads();
    float ls = 0.f;
    for (int s = tid; s < 196; s += 256) ls += __expf(sc[s] - m);
    red[tid] = ls; __syncthreads();
    for (int st = 128; st; st >>= 1) { if (tid < st) red[tid] += red[tid + st]; __syncthreads(); }
    float inv = 1.f / red[0]; __syncthreads();
    for (int s = tid; s < 196; s += 256) als[s] = __expf(sc[s] - m) * inv;
    __syncthreads();
    int c = half * 512 + tid * 2;
    const float* cp = ctx + (long)b * 1024 + c;
    float a0 = 0.f, a1 = 0.f;
    for (int s = 0; s < 196; s += 4) {
#pragma unroll
        for (int u = 0; u < 4; u++) {
            float2 v = *(const float2*)(cp + (long)(s + u) * 65536);
            float al = als[s + u];
            a0 += al * v.x; a1 += al * v.y;
        }
    }
    ushort2 o = { f2b(a0), f2b(a1) };
    *(ushort2*)(xc + (long)(t * 64 + b) * 2560 + 512 + c) = o;
}

// ---------------- GRU gate GEMM (packed virtual N=4096, K-split 2) ----------------
__global__ __launch_bounds__(256) void k_gates(const unsigned short* __restrict__ xct,
                                               const unsigned short* __restrict__ Wg,
                                               float* __restrict__ gparts) {
    int tid = threadIdx.x, lane = tid & 63, w = tid >> 6;
    int vt = blockIdx.x >> 1, kc = blockIdx.x & 1;
    int vn0 = vt * 16;
    int cl = vn0 >> 10;
    int Kc = (cl < 2) ? 2560 : (cl == 2 ? 1536 : 1024);
    int Kh = Kc >> 1;
    int Aoff = (cl == 3) ? 1536 : 0;
    int m0 = w * 16, mr = lane & 15, kb = lane >> 4;
    int vn = vn0 + mr;
    long rowbase;
    if (cl < 2)       rowbase = (long)vn * 2560;
    else if (cl == 2) rowbase = 5242880L + (long)(vn - 2048) * 1536;
    else              rowbase = 6815744L + (long)(vn - 3072) * 1024;
    const unsigned short* ap = xct + (long)(m0 + mr) * 2560 + Aoff + kc * Kh + kb * 8;
    const unsigned short* bp = Wg + rowbase + kc * Kh + kb * 8;
    f32x4 acc = (f32x4){0.f, 0.f, 0.f, 0.f};
#pragma unroll 4
    for (int kk = 0; kk < Kh; kk += 32)
        acc = MFMA(*(const s16x8*)(ap + kk), *(const s16x8*)(bp + kk), acc);
#pragma unroll
    for (int j = 0; j < 4; j++)
        gparts[(long)kc * 262144 + (long)(m0 + kb * 4 + j) * 4096 + vn0 + mr] = acc[j];
}

// ---------------- GRU finish: h' = (1-z)n + z h ; feeds hbf + next xc ----------
__global__ __launch_bounds__(256) void k_hfin(const float* __restrict__ gp,
                                              const float* __restrict__ bih,
                                              const float* __restrict__ bhh,
                                              float* __restrict__ hf32,
                                              unsigned short* __restrict__ hbf,
                                              unsigned short* __restrict__ xc, int t) {
    int i = blockIdx.x * 256 + threadIdx.x;
    int b = i >> 10, j = i & 1023;
    const float* g0 = gp + (long)b * 4096;
    const float* g1 = gp + 262144 + (long)b * 4096;
    float r  = sigmoidf_(g0[j] + g1[j] + bih[j] + bhh[j]);
    float zz = sigmoidf_(g0[1024 + j] + g1[1024 + j] + bih[1024 + j] + bhh[1024 + j]);
    float n  = fast_tanh(g0[2048 + j] + g1[2048 + j] + bih[2048 + j] +
                         r * (g0[3072 + j] + g1[3072 + j] + bhh[2048 + j]));
    float h = (1.f - zz) * n + zz * hf32[i];
    hf32[i] = h;
    unsigned short hb = f2b(h);
    hbf[i] = hb;
    if (t + 1 < TS_) xc[(long)((t + 1) * 64 + b) * 2560 + 1536 + j] = hb;
}

// ---------------- output head via MFMA: obf[b][512] ----------------
__global__ __launch_bounds__(256) void k_out(const unsigned short* __restrict__ hbf,
                                             const unsigned short* __restrict__ xct,
                                             const unsigned short* __restrict__ h2obf,
                                             const float* __restrict__ h2ob,
                                             const unsigned short* __restrict__ octxbf,
                                             const float* __restrict__ octxb,
                                             unsigned short* __restrict__ obf) {
    int tid = threadIdx.x, lane = tid & 63, w = tid >> 6;
    int n0 = blockIdx.x * 16;
    int m0 = w * 16, mr = lane & 15, kb = lane >> 4;
    const unsigned short* ah = hbf + (long)(m0 + mr) * 1024 + kb * 8;
    const unsigned short* az = xct + (long)(m0 + mr) * 2560 + 512 + kb * 8;
    const unsigned short* b1p = h2obf + (long)(n0 + mr) * 1024 + kb * 8;
    const unsigned short* b2p = octxbf + (long)(n0 + mr) * 1024 + kb * 8;
    f32x4 a1 = (f32x4){0.f,0.f,0.f,0.f}, a2 = a1;
#pragma unroll 4
    for (int k0 = 0; k0 < 1024; k0 += 32) {
        a1 = MFMA(*(const s16x8*)(ah + k0), *(const s16x8*)(b1p + k0), a1);
        a2 = MFMA(*(const s16x8*)(az + k0), *(const s16x8*)(b2p + k0), a2);
    }
    int e = n0 + mr;
    float b1v = h2ob[e], b2v = octxb[e];
#pragma unroll
    for (int j = 0; j < 4; j++) {
        int b = m0 + kb * 4 + j;
        float ye = b2f(xct[(long)b * 2560 + e]);
        float val = fast_tanh(a1[j] + b1v) + ye + a2[j] + b2v;
        obf[(long)b * 512 + e] = f2b(fast_tanh(val));
    }
}

// ---------------- vocab logits via MFMA + per-wave LSE partials ----------------
__global__ __launch_bounds__(256) void k_vocab(const unsigned short* __restrict__ obf,
                                               const unsigned short* __restrict__ o2pbf,
                                               const float* __restrict__ bias,
                                               float* __restrict__ pm, float* __restrict__ ps) {
    int tid = threadIdx.x, lane = tid & 63, w = tid >> 6;
    int wid = blockIdx.x * 4 + w;
    int v0 = wid * 16;
    int mr = lane & 15, kb = lane >> 4;
    const unsigned short* bp = o2pbf + (long)(v0 + mr) * 512 + kb * 8;
    const unsigned short* ap = obf + (long)mr * 512 + kb * 8;
    f32x4 acc[4];
#pragma unroll
    for (int i = 0; i < 4; i++) acc[i] = (f32x4){0.f, 0.f, 0.f, 0.f};
#pragma unroll 2
    for (int k0 = 0; k0 < 512; k0 += 32) {
        s16x8 b = *(const s16x8*)(bp + k0);
#pragma unroll
        for (int mt = 0; mt < 4; mt++) {
            s16x8 a = *(const s16x8*)(ap + (long)mt * 16 * 512 + k0);
            acc[mt] = MFMA(a, b, acc[mt]);
        }
    }
    float bv = bias[v0 + mr];
#pragma unroll
    for (int mt = 0; mt < 4; mt++)
#pragma unroll
        for (int j = 0; j < 4; j++) {
            float x = acc[mt][j] + bv;
            float mm = x;
            mm = fmaxf(mm, __shfl_xor(mm, 1, 64));
            mm = fmaxf(mm, __shfl_xor(mm, 2, 64));
            mm = fmaxf(mm, __shfl_xor(mm, 4, 64));
            mm = fmaxf(mm, __shfl_xor(mm, 8, 64));
            float ee = __expf(x - mm);
            ee += __shfl_xor(ee, 1, 64);
            ee += __shfl_xor(ee, 2, 64);
            ee += __shfl_xor(ee, 4, 64);
            ee += __shfl_xor(ee, 8, 64);
            if (mr == 0) {
                int b = mt * 16 + kb * 4 + j;
                pm[(long)wid * 64 + b] = mm;
                ps[(long)wid * 64 + b] = ee;
            }
        }
}

// ---------------- reduce partials -> lse, target logit, accumulate NLL ----------
__global__ __launch_bounds__(256) void k_lse(const float* __restrict__ pm, const float* __restrict__ ps,
                                             const unsigned short* __restrict__ obf,
                                             const float* __restrict__ W, const float* __restrict__ bias,
                                             const int* __restrict__ y, float* __restrict__ out, int t) {
    __shared__ float rm[256], rs[256], rd[256];
    int tid = threadIdx.x, b = blockIdx.x;
    float m = -1e30f, s = 0.f;
    for (int i = tid; i < 2000; i += 256) {
        float mi = pm[(long)i * 64 + b], si = ps[(long)i * 64 + b];
        float nm = fmaxf(m, mi);
        s = s * __expf(m - nm) + si * __expf(mi - nm);
        m = nm;
    }
    int tgt = y[(t + 1) * 64 + b];
    const float* wr = W + (long)tgt * 512;
    float d = 0.f;
    for (int e = tid; e < 512; e += 256) d += b2f(obf[(long)b * 512 + e]) * wr[e];
    rm[tid] = m; rs[tid] = s; rd[tid] = d;
    __syncthreads();
    for (int st = 128; st; st >>= 1) {
        if (tid < st) {
            float m2 = rm[tid + st], s2 = rs[tid + st];
            float nm = fmaxf(rm[tid], m2);
            rs[tid] = rs[tid] * __expf(rm[tid] - nm) + s2 * __expf(m2 - nm);
            rm[tid] = nm;
            rd[tid] += rd[tid + st];
        }
        __syncthreads();
    }
    if (tid == 0) {
        float lse = rm[0] + __logf(rs[0]);
        float lt = rd[0] + bias[tgt];
        float nll = (tgt != 0) ? (lse - lt) : 0.f;
        atomicAdd(out, nll);
    }
}

extern "C" void kernel_launch(void* const* d_in, const int* in_sizes, int n_in,
                              void* d_out, int out_size, void* d_ws, size_t ws_size,
                              hipStream_t stream) {
    const float* ctx     = (const float*)d_in[0];
    const int*   y       = (const int*)d_in[1];
    const float* embW    = (const float*)d_in[2];
    const float* att_c2c = (const float*)d_in[3];
    const float* att_h2c = (const float*)d_in[4];
    const float* mlp     = (const float*)d_in[5];
    const float* Wih     = (const float*)d_in[6];
    const float* bih     = (const float*)d_in[7];
    const float* Whh     = (const float*)d_in[8];
    const float* bhh     = (const float*)d_in[9];
    const float* h2oW    = (const float*)d_in[10];
    const float* h2ob    = (const float*)d_in[11];
    const float* octxW   = (const float*)d_in[12];
    const float* octxb   = (const float*)d_in[13];
    const float* o2pW    = (const float*)d_in[14];
    const float* o2pb    = (const float*)d_in[15];
    float* out = (float*)d_out;

    char* base = (char*)d_ws;
    unsigned short* cpbf   = (unsigned short*)base; base += 25690112L;   // [12544][1024]
    unsigned short* c2cT   = (unsigned short*)base; base += 2097152L;    // [n][k]
    unsigned short* attbf  = (unsigned short*)base; base += 2097152L;    // [n=c][k=h]
    unsigned short* Wg     = (unsigned short*)base; base += 15728640L;   // packed gates
    unsigned short* h2obf  = (unsigned short*)base; base += 1048576L;
    unsigned short* octxbf = (unsigned short*)base; base += 1048576L;
    unsigned short* o2pbf  = (unsigned short*)base; base += 32768000L;
    unsigned short* xc     = (unsigned short*)base; base += 6225920L;    // [19][64][2560]
    unsigned short* hbf    = (unsigned short*)base; base += 131072L;     // [64][1024]
    unsigned short* obf    = (unsigned short*)base; base += 65536L;      // [64][512]
    float* hf32   = (float*)base; base += 262144L;                        // [64][1024]
    float* hpp    = (float*)base; base += 524288L;                        // [2][64][1024]
    float* gparts = (float*)base; base += 2097152L;                       // [2][64][4096]
    float* scores = (float*)base; base += 50176L;                         // [64][196]
    float* pm     = (float*)base; base += 512000L;                        // [2000][64]
    float* ps     = (float*)base; base += 512000L;

    hipMemsetAsync(d_out, 0, sizeof(float), stream);
    hipMemsetAsync(hf32, 0, 262144, stream);
    hipMemsetAsync(hbf, 0, 131072, stream);
    hipMemsetAsync(xc, 0, 6225920, stream);

    // one-time prep (captured in graph, runs each replay)
    k_yemb<<<TS_ * 64, 256, 0, stream>>>(y, embW, xc);
    k_tcvt<<<dim3(32, 32), dim3(32, 8), 0, stream>>>(att_c2c, c2cT);
    k_tcvt<<<dim3(32, 32), dim3(32, 8), 0, stream>>>(att_h2c, attbf);
    k_cvt<<<512, 256, 0, stream>>>(h2oW, h2obf, 524288L);
    k_cvt<<<512, 256, 0, stream>>>(octxW, octxbf, 524288L);
    k_cvt<<<2048, 256, 0, stream>>>(o2pW, o2pbf, 16384000L);
    k_prepw<<<4096, 256, 0, stream>>>(Wih, Whh, Wg);
    k_gemm<<<1568, 256, 0, stream>>>(ctx, c2cT, cpbf);

    for (int t = 0; t < TS_; t++) {
        const unsigned short* xct = xc + (long)t * 64 * 2560;
        k_hproj<<<128, 256, 0, stream>>>(hbf, attbf, hpp);
        k_scores<<<3136, 256, 0, stream>>>(cpbf, hpp, mlp, scores);
        k_z<<<128, 256, 0, stream>>>(scores, ctx, xc, t);
        k_gates<<<512, 256, 0, stream>>>(xct, Wg, gparts);
        k_hfin<<<256, 256, 0, stream>>>(gparts, bih, bhh, hf32, hbf, xc, t);
        k_out<<<32, 256, 0, stream>>>(hbf, xct, h2obf, h2ob, octxbf, octxb, obf);
        k_vocab<<<500, 256, 0, stream>>>(obf, o2pbf, o2pb, pm, ps);
        k_lse<<<64, 256, 0, stream>>>(pm, ps, obf, o2pW, o2pb, y, out, t);
    }
}